// Round 6
// baseline (103.767 us; speedup 1.0000x reference)
//
#include <hip/hip_runtime.h>
#include <cfloat>

// EmbeddingBag(mean) ++ EmbeddingBag(max) -> Linear(no bias)
// feat[T] i32, offs[B] i32 (sorted, offs[0]=0), W[100000][128] f32,
// L[128][256] f32 ; out: [B][128] f32
// Bag b = tokens [offs[b], offs[b+1]) (offs[B]=T); empty bag -> mean=max=0.
//
// Two-kernel token-uniform design:
//  k1: each wave owns TPW contiguous tokens (perfect balance), accumulates
//      per-bag partials in registers, merges via atomicAdd / atomicMax(ukey).
//  k2: finalize mean/max from ws, small dense [8x256]x[256x128] per block.

constexpr int D     = 128;
constexpr int TYPES = 128;
constexpr int TPW   = 64;    // tokens per wave in k1
constexpr int K2BPB = 8;     // bags per block in k2

// order-preserving float->uint key (monotone): uint-compare == float-compare
__device__ __forceinline__ unsigned fkey(float f) {
    unsigned b = __float_as_uint(f);
    return (b & 0x80000000u) ? ~b : (b | 0x80000000u);
}
__device__ __forceinline__ float funkey(unsigned k) {
    return __uint_as_float((k & 0x80000000u) ? (k & 0x7FFFFFFFu) : ~k);
}

__global__ __launch_bounds__(256, 8)
void k1_gather(const int* __restrict__ feat, const int* __restrict__ offs,
               const float* __restrict__ W,
               float* __restrict__ wsum, unsigned* __restrict__ wkey,
               int T, int B)
{
    const int wave = (blockIdx.x << 2) + (threadIdx.x >> 6);
    const int lane = threadIdx.x & 63;
    const int slot = lane >> 5;   // 0/1: alternating tokens
    const int g    = lane & 31;   // dims 4g..4g+3
    const int i0   = wave * TPW;
    if (i0 >= T) return;
    const int iend = min(i0 + TPW, T);

    // greatest seg with offs[seg] <= i0  (offs is 32KB -> L1/L2-hot)
    int lo = 0, hi = B;
    while (lo < hi) {
        const int mid = (lo + hi) >> 1;
        if (offs[mid] <= i0) lo = mid + 1; else hi = mid;
    }
    int seg    = lo - 1;
    int segEnd = (seg + 1 < B) ? offs[seg + 1] : T;

    const float* __restrict__ Wg = W + 4 * g;
    float4 s4 = make_float4(0.f, 0.f, 0.f, 0.f);
    float4 m4 = make_float4(-FLT_MAX, -FLT_MAX, -FLT_MAX, -FLT_MAX);
    bool dirty = false;
    int i = i0;

    while (true) {
        const int stop = min(iend, segEnd);
        int len = stop - i;
        if (len > 0) {
            dirty = true;
            // full 16-token batches: 8 tokens/slot, 8 gathers in flight/lane
            for (; len >= 16; len -= 16, i += 16) {
                int idx[8];
                #pragma unroll
                for (int u = 0; u < 8; ++u) idx[u] = feat[i + 2 * u + slot];
                float4 v[8];
                #pragma unroll
                for (int u = 0; u < 8; ++u)
                    v[u] = *reinterpret_cast<const float4*>(Wg + (size_t)idx[u] * D);
                #pragma unroll
                for (int u = 0; u < 8; ++u) {
                    s4.x += v[u].x; s4.y += v[u].y;
                    s4.z += v[u].z; s4.w += v[u].w;
                    m4.x = fmaxf(m4.x, v[u].x); m4.y = fmaxf(m4.y, v[u].y);
                    m4.z = fmaxf(m4.z, v[u].z); m4.w = fmaxf(m4.w, v[u].w);
                }
            }
            if (len > 0) {   // predicated tail, 1..15 tokens, still 8-deep
                int idx[8];
                #pragma unroll
                for (int u = 0; u < 8; ++u) {
                    const int t = i + 2 * u + slot;
                    idx[u] = feat[t < stop ? t : stop - 1];
                }
                float4 v[8];
                #pragma unroll
                for (int u = 0; u < 8; ++u)
                    v[u] = *reinterpret_cast<const float4*>(Wg + (size_t)idx[u] * D);
                #pragma unroll
                for (int u = 0; u < 8; ++u) {
                    const bool val = (i + 2 * u + slot) < stop;
                    s4.x += val ? v[u].x : 0.f;
                    s4.y += val ? v[u].y : 0.f;
                    s4.z += val ? v[u].z : 0.f;
                    s4.w += val ? v[u].w : 0.f;
                    m4.x = fmaxf(m4.x, val ? v[u].x : -FLT_MAX);
                    m4.y = fmaxf(m4.y, val ? v[u].y : -FLT_MAX);
                    m4.z = fmaxf(m4.z, val ? v[u].z : -FLT_MAX);
                    m4.w = fmaxf(m4.w, val ? v[u].w : -FLT_MAX);
                }
                i = stop;
            }
        }

        const bool done = (i >= iend);
        if (dirty && (done || i >= segEnd)) {
            // merge the two slot-halves (lane ^ 32), then 32 lanes -> atomics
            s4.x += __shfl_xor(s4.x, 32); s4.y += __shfl_xor(s4.y, 32);
            s4.z += __shfl_xor(s4.z, 32); s4.w += __shfl_xor(s4.w, 32);
            m4.x = fmaxf(m4.x, __shfl_xor(m4.x, 32));
            m4.y = fmaxf(m4.y, __shfl_xor(m4.y, 32));
            m4.z = fmaxf(m4.z, __shfl_xor(m4.z, 32));
            m4.w = fmaxf(m4.w, __shfl_xor(m4.w, 32));
            if (lane < 32) {
                float* ps = wsum + (size_t)seg * D + 4 * g;
                atomicAdd(ps + 0, s4.x); atomicAdd(ps + 1, s4.y);
                atomicAdd(ps + 2, s4.z); atomicAdd(ps + 3, s4.w);
                unsigned* pk = wkey + (size_t)seg * D + 4 * g;
                atomicMax(pk + 0, fkey(m4.x)); atomicMax(pk + 1, fkey(m4.y));
                atomicMax(pk + 2, fkey(m4.z)); atomicMax(pk + 3, fkey(m4.w));
            }
            s4 = make_float4(0.f, 0.f, 0.f, 0.f);
            m4 = make_float4(-FLT_MAX, -FLT_MAX, -FLT_MAX, -FLT_MAX);
            dirty = false;
        }
        if (done) break;
        ++seg;
        segEnd = (seg + 1 < B) ? offs[seg + 1] : T;
    }
}

__global__ __launch_bounds__(256, 8)
void k2_linear(const int* __restrict__ offs,
               const float* __restrict__ wsum, const unsigned* __restrict__ wkey,
               const float* __restrict__ L, float* __restrict__ out,
               int T, int B)
{
    __shared__ float men[K2BPB][2 * D];       // 8 KB
    __shared__ float partial[K2BPB][TYPES];   // 4 KB
    const int tid  = threadIdx.x;
    const int bag0 = blockIdx.x * K2BPB;

    // finalize mean / max into LDS
    for (int e = tid; e < K2BPB * 2 * D; e += 256) {
        const int r   = e >> 8;      // bag slot (2*D == 256)
        const int j   = e & 255;
        const int bag = bag0 + r;
        float v = 0.f;
        if (bag < B) {
            const int st  = offs[bag];
            const int en  = (bag + 1 < B) ? offs[bag + 1] : T;
            const int cnt = en - st;
            if (cnt > 0) {
                if (j < D) v = wsum[(size_t)bag * D + j] / (float)cnt;
                else       v = funkey(wkey[(size_t)bag * D + (j - D)]);
            }
        }
        men[r][j] = v;
    }
    __syncthreads();

    // out[bag][o] = sum_k men[bag][k] * L[o][k]
    const int o = tid & (TYPES - 1);
    const int h = tid >> 7;          // K-half: 0 or 1
    float acc[K2BPB];
    #pragma unroll
    for (int b = 0; b < K2BPB; ++b) acc[b] = 0.f;

    const float* Lrow = L + (size_t)o * (2 * D) + h * D;
    #pragma unroll 4
    for (int k4 = 0; k4 < D / 4; ++k4) {
        const float4 lv = *reinterpret_cast<const float4*>(Lrow + 4 * k4);
        #pragma unroll
        for (int b = 0; b < K2BPB; ++b) {
            const float4 mv = *reinterpret_cast<const float4*>(&men[b][h * D + 4 * k4]);
            acc[b] = fmaf(lv.x, mv.x, acc[b]);
            acc[b] = fmaf(lv.y, mv.y, acc[b]);
            acc[b] = fmaf(lv.z, mv.z, acc[b]);
            acc[b] = fmaf(lv.w, mv.w, acc[b]);
        }
    }
    if (h == 1) {
        #pragma unroll
        for (int b = 0; b < K2BPB; ++b) partial[b][o] = acc[b];
    }
    __syncthreads();
    if (h == 0) {
        #pragma unroll
        for (int b = 0; b < K2BPB; ++b) {
            const int bag = bag0 + b;
            if (bag < B)
                out[(size_t)bag * TYPES + o] = acc[b] + partial[b][o];
        }
    }
}

// ---------------- fallback (round-4 kernel) if ws is too small --------------
constexpr int FBPB = 4;
__global__ __launch_bounds__(512, 8)
void embbag_fallback(const int* __restrict__ feat, const int* __restrict__ offs,
                     const float* __restrict__ W, const float* __restrict__ L,
                     float* __restrict__ out, int T, int B)
{
    __shared__ float4 men[FBPB][64];
    __shared__ float4 redS[FBPB][2][32];
    __shared__ float4 redM[FBPB][2][32];
    __shared__ float  partial[3][FBPB][TYPES];
    const int tid = threadIdx.x, wv = tid >> 6, lane = tid & 63;
    const int bi = wv >> 1, wh = wv & 1, slot = lane >> 5, g = lane & 31;
    const int bag0 = blockIdx.x * FBPB, bag = bag0 + bi;
    int start = 0, end = 0;
    if (bag < B) { start = offs[bag]; end = (bag + 1 < B) ? offs[bag + 1] : T; }
    const int n = end - start, q = wh * 2 + slot;
    const int qa = start + (n * q) / 4, qb = start + (n * (q + 1)) / 4;
    float4 s4 = make_float4(0.f, 0.f, 0.f, 0.f);
    float4 m4 = make_float4(-FLT_MAX, -FLT_MAX, -FLT_MAX, -FLT_MAX);
    const float* Wg = W + 4 * g;
    int i = qa;
    for (; i + 8 <= qb; i += 8) {
        int idx[8];
        #pragma unroll
        for (int j = 0; j < 8; ++j) idx[j] = feat[i + j];
        #pragma unroll
        for (int j = 0; j < 8; ++j) {
            const float4 v = *reinterpret_cast<const float4*>(Wg + (size_t)idx[j] * D);
            s4.x += v.x; s4.y += v.y; s4.z += v.z; s4.w += v.w;
            m4.x = fmaxf(m4.x, v.x); m4.y = fmaxf(m4.y, v.y);
            m4.z = fmaxf(m4.z, v.z); m4.w = fmaxf(m4.w, v.w);
        }
    }
    for (; i < qb; ++i) {
        const int idx = feat[i];
        const float4 v = *reinterpret_cast<const float4*>(Wg + (size_t)idx * D);
        s4.x += v.x; s4.y += v.y; s4.z += v.z; s4.w += v.w;
        m4.x = fmaxf(m4.x, v.x); m4.y = fmaxf(m4.y, v.y);
        m4.z = fmaxf(m4.z, v.z); m4.w = fmaxf(m4.w, v.w);
    }
    s4.x += __shfl_xor(s4.x, 32); s4.y += __shfl_xor(s4.y, 32);
    s4.z += __shfl_xor(s4.z, 32); s4.w += __shfl_xor(s4.w, 32);
    m4.x = fmaxf(m4.x, __shfl_xor(m4.x, 32));
    m4.y = fmaxf(m4.y, __shfl_xor(m4.y, 32));
    m4.z = fmaxf(m4.z, __shfl_xor(m4.z, 32));
    m4.w = fmaxf(m4.w, __shfl_xor(m4.w, 32));
    if (lane < 32) { redS[bi][wh][g] = s4; redM[bi][wh][g] = m4; }
    __syncthreads();
    if (wh == 0 && lane < 32) {
        const float4 a0 = redS[bi][0][g], a1 = redS[bi][1][g];
        const float4 b0 = redM[bi][0][g], b1 = redM[bi][1][g];
        const bool empty = (n <= 0);
        const float inv = 1.0f / (float)(empty ? 1 : n);
        men[bi][g] = make_float4((a0.x+a1.x)*inv, (a0.y+a1.y)*inv,
                                 (a0.z+a1.z)*inv, (a0.w+a1.w)*inv);
        men[bi][32+g] = empty ? make_float4(0.f,0.f,0.f,0.f)
            : make_float4(fmaxf(b0.x,b1.x), fmaxf(b0.y,b1.y),
                          fmaxf(b0.z,b1.z), fmaxf(b0.w,b1.w));
    }
    __syncthreads();
    const int o = tid & (TYPES - 1), h = tid >> 7;
    float acc[FBPB];
    #pragma unroll
    for (int b = 0; b < FBPB; ++b) acc[b] = 0.f;
    const float* Lrow = L + (size_t)o * (2 * D) + h * 64;
    #pragma unroll
    for (int k4 = 0; k4 < 16; ++k4) {
        const float4 lv = *reinterpret_cast<const float4*>(Lrow + 4 * k4);
        #pragma unroll
        for (int b = 0; b < FBPB; ++b) {
            const float4 mv = men[b][h * 16 + k4];
            acc[b] = fmaf(lv.x, mv.x, acc[b]);
            acc[b] = fmaf(lv.y, mv.y, acc[b]);
            acc[b] = fmaf(lv.z, mv.z, acc[b]);
            acc[b] = fmaf(lv.w, mv.w, acc[b]);
        }
    }
    if (h > 0) {
        #pragma unroll
        for (int b = 0; b < FBPB; ++b) partial[h-1][b][o] = acc[b];
    }
    __syncthreads();
    if (h == 0) {
        #pragma unroll
        for (int b = 0; b < FBPB; ++b) {
            const int bg = bag0 + b;
            if (bg < B)
                out[(size_t)bg*TYPES+o] =
                    acc[b] + partial[0][b][o] + partial[1][b][o] + partial[2][b][o];
        }
    }
}

extern "C" void kernel_launch(void* const* d_in, const int* in_sizes, int n_in,
                              void* d_out, int out_size, void* d_ws, size_t ws_size,
                              hipStream_t stream)
{
    const int*   feat = (const int*)d_in[0];
    const int*   offs = (const int*)d_in[1];
    const float* W    = (const float*)d_in[2];
    const float* L    = (const float*)d_in[3];
    float*       out  = (float*)d_out;
    const int T = in_sizes[0];
    const int B = in_sizes[1];

    const size_t need = (size_t)B * D * (sizeof(float) + sizeof(unsigned));
    if (ws_size < need) {
        const int grid = (B + FBPB - 1) / FBPB;
        embbag_fallback<<<grid, 512, 0, stream>>>(feat, offs, W, L, out, T, B);
        return;
    }

    float*    wsum = (float*)d_ws;
    unsigned* wkey = (unsigned*)((char*)d_ws + (size_t)B * D * sizeof(float));
    (void)hipMemsetAsync(d_ws, 0, need, stream);  // 0 == key(-inf): safe identity

    const int nwave = (T + TPW - 1) / TPW;
    const int grid1 = (nwave + 3) / 4;       // 4 waves per 256-thr block
    k1_gather<<<grid1, 256, 0, stream>>>(feat, offs, W, wsum, wkey, T, B);

    const int grid2 = (B + K2BPB - 1) / K2BPB;
    k2_linear<<<grid2, 256, 0, stream>>>(offs, wsum, wkey, L, out, T, B);
}

// Round 7
// 77.829 us; speedup vs baseline: 1.3333x; 1.3333x over previous
//
#include <hip/hip_runtime.h>
#include <cfloat>

// EmbeddingBag(mean) ++ EmbeddingBag(max) -> Linear(no bias)
// feat[T] i32, offs[B] i32 (sorted, offs[0]=0), W[100000][128] f32,
// L[128][256] f32 ; out: [B][128] f32
// Bag b = tokens [offs[b], offs[b+1]) (offs[B]=T); empty bag -> mean=max=0.
//
// Three-kernel token-uniform design:
//  k0: per-wave starting segment (binary search), fully parallel.
//  k1: each wave owns TPW contiguous tokens; token ids prefetched into a
//      register and distributed via __shfl; 8 independent row-gathers in
//      flight; per-segment partials merged via atomicAdd / atomicMax(key).
//  k2: finalize mean/max from ws, small dense [8x256]x[256x128] per block.

constexpr int D     = 128;
constexpr int TYPES = 128;
constexpr int TPW   = 64;    // tokens per wave in k1
constexpr int K2BPB = 8;     // bags per block in k2

// order-preserving float->uint key (monotone): uint-compare == float-compare
__device__ __forceinline__ unsigned fkey(float f) {
    unsigned b = __float_as_uint(f);
    return (b & 0x80000000u) ? ~b : (b | 0x80000000u);
}
__device__ __forceinline__ float funkey(unsigned k) {
    return __uint_as_float((k & 0x80000000u) ? (k & 0x7FFFFFFFu) : ~k);
}

// ---------------- k0: per-wave starting segment ----------------------------
__global__ __launch_bounds__(256)
void k0_seg(const int* __restrict__ offs, int* __restrict__ waveseg,
            int T, int B, int nwave)
{
    const int w = blockIdx.x * 256 + threadIdx.x;
    if (w >= nwave) return;
    const int i0 = w * TPW;
    int lo = 0, hi = B;
    while (lo < hi) {
        const int mid = (lo + hi) >> 1;
        if (offs[mid] <= i0) lo = mid + 1; else hi = mid;
    }
    waveseg[w] = lo - 1;
}

// ---------------- k1: gather + per-segment partial reduce ------------------
__global__ __launch_bounds__(256, 4)
void k1_gather(const int* __restrict__ feat, const int* __restrict__ offs,
               const int* __restrict__ waveseg, const float* __restrict__ W,
               float* __restrict__ wsum, unsigned* __restrict__ wkey,
               int T, int B)
{
    const int wave = blockIdx.x * 4 + (threadIdx.x >> 6);
    const int lane = threadIdx.x & 63;
    const int slot = lane >> 5;   // 0/1: alternating tokens
    const int g    = lane & 31;   // dims 4g..4g+3
    const int i0   = wave * TPW;
    if (i0 >= T) return;
    const int iend = min(i0 + TPW, T);

    // wave's token ids: one coalesced 256B load, lane j holds token i0+j
    const int idxreg = feat[min(i0 + lane, T - 1)];

    int seg    = waveseg[wave];
    int segEnd = (seg + 1 < B) ? offs[seg + 1] : T;

    const float* __restrict__ Wg = W + 4 * g;
    float4 s4 = make_float4(0.f, 0.f, 0.f, 0.f);
    float4 m4 = make_float4(-FLT_MAX, -FLT_MAX, -FLT_MAX, -FLT_MAX);
    bool dirty = false;
    int i = i0;

    while (true) {
        const int stop = min(iend, segEnd);
        int len = stop - i;
        if (len > 0) {
            dirty = true;
            // full 16-token batches: 8 tokens/slot, 8 gathers in flight/lane
            for (; len >= 16; len -= 16, i += 16) {
                int idx[8];
                #pragma unroll
                for (int u = 0; u < 8; ++u)
                    idx[u] = __shfl(idxreg, (i - i0) + 2 * u + slot);
                float4 v[8];
                #pragma unroll
                for (int u = 0; u < 8; ++u)
                    v[u] = *reinterpret_cast<const float4*>(Wg + (size_t)idx[u] * D);
                #pragma unroll
                for (int u = 0; u < 8; ++u) {
                    s4.x += v[u].x; s4.y += v[u].y;
                    s4.z += v[u].z; s4.w += v[u].w;
                    m4.x = fmaxf(m4.x, v[u].x); m4.y = fmaxf(m4.y, v[u].y);
                    m4.z = fmaxf(m4.z, v[u].z); m4.w = fmaxf(m4.w, v[u].w);
                }
            }
            if (len > 0) {   // predicated tail, 1..15 tokens, still 8-deep
                int idx[8]; bool val[8];
                #pragma unroll
                for (int u = 0; u < 8; ++u) {
                    const int t = i + 2 * u + slot;
                    val[u] = (t < stop);
                    idx[u] = __shfl(idxreg, (val[u] ? t : stop - 1) - i0);
                }
                float4 v[8];
                #pragma unroll
                for (int u = 0; u < 8; ++u)
                    v[u] = *reinterpret_cast<const float4*>(Wg + (size_t)idx[u] * D);
                #pragma unroll
                for (int u = 0; u < 8; ++u) {
                    s4.x += val[u] ? v[u].x : 0.f;
                    s4.y += val[u] ? v[u].y : 0.f;
                    s4.z += val[u] ? v[u].z : 0.f;
                    s4.w += val[u] ? v[u].w : 0.f;
                    m4.x = fmaxf(m4.x, val[u] ? v[u].x : -FLT_MAX);
                    m4.y = fmaxf(m4.y, val[u] ? v[u].y : -FLT_MAX);
                    m4.z = fmaxf(m4.z, val[u] ? v[u].z : -FLT_MAX);
                    m4.w = fmaxf(m4.w, val[u] ? v[u].w : -FLT_MAX);
                }
                i = stop;
            }
        }

        const bool done = (i >= iend);
        if (dirty && (done || i >= segEnd)) {
            // merge the two slot-halves (lane ^ 32); both slots hold merged
            s4.x += __shfl_xor(s4.x, 32); s4.y += __shfl_xor(s4.y, 32);
            s4.z += __shfl_xor(s4.z, 32); s4.w += __shfl_xor(s4.w, 32);
            m4.x = fmaxf(m4.x, __shfl_xor(m4.x, 32));
            m4.y = fmaxf(m4.y, __shfl_xor(m4.y, 32));
            m4.z = fmaxf(m4.z, __shfl_xor(m4.z, 32));
            m4.w = fmaxf(m4.w, __shfl_xor(m4.w, 32));
            // all 64 lanes flush: slot0 -> dims 4g..4g+1, slot1 -> 4g+2..4g+3
            const float a0 = slot ? s4.z : s4.x;
            const float a1 = slot ? s4.w : s4.y;
            const float b0 = slot ? m4.z : m4.x;
            const float b1 = slot ? m4.w : m4.y;
            float*    ps = wsum + (size_t)seg * D + 4 * g + 2 * slot;
            unsigned* pk = wkey + (size_t)seg * D + 4 * g + 2 * slot;
            atomicAdd(ps + 0, a0); atomicAdd(ps + 1, a1);
            atomicMax(pk + 0, fkey(b0)); atomicMax(pk + 1, fkey(b1));
            s4 = make_float4(0.f, 0.f, 0.f, 0.f);
            m4 = make_float4(-FLT_MAX, -FLT_MAX, -FLT_MAX, -FLT_MAX);
            dirty = false;
        }
        if (done) break;
        ++seg;
        segEnd = (seg + 1 < B) ? offs[seg + 1] : T;
    }
}

// ---------------- k2: finalize + linear -------------------------------------
__global__ __launch_bounds__(256, 8)
void k2_linear(const int* __restrict__ offs,
               const float* __restrict__ wsum, const unsigned* __restrict__ wkey,
               const float* __restrict__ L, float* __restrict__ out,
               int T, int B)
{
    __shared__ float men[K2BPB][2 * D];       // 8 KB
    __shared__ float partial[K2BPB][TYPES];   // 4 KB
    const int tid  = threadIdx.x;
    const int bag0 = blockIdx.x * K2BPB;

    // finalize mean / max into LDS (float4-vectorized: 512 groups, 2/thread)
    for (int e = tid; e < K2BPB * 2 * D / 4; e += 256) {
        const int r   = e >> 6;          // bag slot (64 float4 per bag row)
        const int c   = e & 63;          // float4 column
        const int bag = bag0 + r;
        float4 v = make_float4(0.f, 0.f, 0.f, 0.f);
        if (bag < B) {
            const int st  = offs[bag];
            const int en  = (bag + 1 < B) ? offs[bag + 1] : T;
            const int cnt = en - st;
            if (cnt > 0) {
                if (c < 32) {
                    const float4 s =
                        *reinterpret_cast<const float4*>(wsum + (size_t)bag * D + 4 * c);
                    const float inv = 1.0f / (float)cnt;
                    v = make_float4(s.x * inv, s.y * inv, s.z * inv, s.w * inv);
                } else {
                    const uint4 k =
                        *reinterpret_cast<const uint4*>(wkey + (size_t)bag * D + 4 * (c - 32));
                    v = make_float4(funkey(k.x), funkey(k.y),
                                    funkey(k.z), funkey(k.w));
                }
            }
        }
        *reinterpret_cast<float4*>(&men[r][4 * c]) = v;
    }
    __syncthreads();

    // out[bag][o] = sum_k men[bag][k] * L[o][k]
    const int o = tid & (TYPES - 1);
    const int h = tid >> 7;          // K-half: 0 or 1
    float acc[K2BPB];
    #pragma unroll
    for (int b = 0; b < K2BPB; ++b) acc[b] = 0.f;

    const float* Lrow = L + (size_t)o * (2 * D) + h * D;
    #pragma unroll 4
    for (int k4 = 0; k4 < D / 4; ++k4) {
        const float4 lv = *reinterpret_cast<const float4*>(Lrow + 4 * k4);
        #pragma unroll
        for (int b = 0; b < K2BPB; ++b) {
            const float4 mv = *reinterpret_cast<const float4*>(&men[b][h * D + 4 * k4]);
            acc[b] = fmaf(lv.x, mv.x, acc[b]);
            acc[b] = fmaf(lv.y, mv.y, acc[b]);
            acc[b] = fmaf(lv.z, mv.z, acc[b]);
            acc[b] = fmaf(lv.w, mv.w, acc[b]);
        }
    }
    if (h == 1) {
        #pragma unroll
        for (int b = 0; b < K2BPB; ++b) partial[b][o] = acc[b];
    }
    __syncthreads();
    if (h == 0) {
        #pragma unroll
        for (int b = 0; b < K2BPB; ++b) {
            const int bag = bag0 + b;
            if (bag < B)
                out[(size_t)bag * TYPES + o] = acc[b] + partial[b][o];
        }
    }
}

// ---------------- fallback (round-4 kernel) if ws is too small --------------
constexpr int FBPB = 4;
__global__ __launch_bounds__(512, 8)
void embbag_fallback(const int* __restrict__ feat, const int* __restrict__ offs,
                     const float* __restrict__ W, const float* __restrict__ L,
                     float* __restrict__ out, int T, int B)
{
    __shared__ float4 men[FBPB][64];
    __shared__ float4 redS[FBPB][2][32];
    __shared__ float4 redM[FBPB][2][32];
    __shared__ float  partial[3][FBPB][TYPES];
    const int tid = threadIdx.x, wv = tid >> 6, lane = tid & 63;
    const int bi = wv >> 1, wh = wv & 1, slot = lane >> 5, g = lane & 31;
    const int bag0 = blockIdx.x * FBPB, bag = bag0 + bi;
    int start = 0, end = 0;
    if (bag < B) { start = offs[bag]; end = (bag + 1 < B) ? offs[bag + 1] : T; }
    const int n = end - start, q = wh * 2 + slot;
    const int qa = start + (n * q) / 4, qb = start + (n * (q + 1)) / 4;
    float4 s4 = make_float4(0.f, 0.f, 0.f, 0.f);
    float4 m4 = make_float4(-FLT_MAX, -FLT_MAX, -FLT_MAX, -FLT_MAX);
    const float* Wg = W + 4 * g;
    int i = qa;
    for (; i + 8 <= qb; i += 8) {
        int idx[8];
        #pragma unroll
        for (int j = 0; j < 8; ++j) idx[j] = feat[i + j];
        #pragma unroll
        for (int j = 0; j < 8; ++j) {
            const float4 v = *reinterpret_cast<const float4*>(Wg + (size_t)idx[j] * D);
            s4.x += v.x; s4.y += v.y; s4.z += v.z; s4.w += v.w;
            m4.x = fmaxf(m4.x, v.x); m4.y = fmaxf(m4.y, v.y);
            m4.z = fmaxf(m4.z, v.z); m4.w = fmaxf(m4.w, v.w);
        }
    }
    for (; i < qb; ++i) {
        const int idx = feat[i];
        const float4 v = *reinterpret_cast<const float4*>(Wg + (size_t)idx * D);
        s4.x += v.x; s4.y += v.y; s4.z += v.z; s4.w += v.w;
        m4.x = fmaxf(m4.x, v.x); m4.y = fmaxf(m4.y, v.y);
        m4.z = fmaxf(m4.z, v.z); m4.w = fmaxf(m4.w, v.w);
    }
    s4.x += __shfl_xor(s4.x, 32); s4.y += __shfl_xor(s4.y, 32);
    s4.z += __shfl_xor(s4.z, 32); s4.w += __shfl_xor(s4.w, 32);
    m4.x = fmaxf(m4.x, __shfl_xor(m4.x, 32));
    m4.y = fmaxf(m4.y, __shfl_xor(m4.y, 32));
    m4.z = fmaxf(m4.z, __shfl_xor(m4.z, 32));
    m4.w = fmaxf(m4.w, __shfl_xor(m4.w, 32));
    if (lane < 32) { redS[bi][wh][g] = s4; redM[bi][wh][g] = m4; }
    __syncthreads();
    if (wh == 0 && lane < 32) {
        const float4 a0 = redS[bi][0][g], a1 = redS[bi][1][g];
        const float4 b0 = redM[bi][0][g], b1 = redM[bi][1][g];
        const bool empty = (n <= 0);
        const float inv = 1.0f / (float)(empty ? 1 : n);
        men[bi][g] = make_float4((a0.x+a1.x)*inv, (a0.y+a1.y)*inv,
                                 (a0.z+a1.z)*inv, (a0.w+a1.w)*inv);
        men[bi][32+g] = empty ? make_float4(0.f,0.f,0.f,0.f)
            : make_float4(fmaxf(b0.x,b1.x), fmaxf(b0.y,b1.y),
                          fmaxf(b0.z,b1.z), fmaxf(b0.w,b1.w));
    }
    __syncthreads();
    const int o = tid & (TYPES - 1), h = tid >> 7;
    float acc[FBPB];
    #pragma unroll
    for (int b = 0; b < FBPB; ++b) acc[b] = 0.f;
    const float* Lrow = L + (size_t)o * (2 * D) + h * 64;
    #pragma unroll
    for (int k4 = 0; k4 < 16; ++k4) {
        const float4 lv = *reinterpret_cast<const float4*>(Lrow + 4 * k4);
        #pragma unroll
        for (int b = 0; b < FBPB; ++b) {
            const float4 mv = men[b][h * 16 + k4];
            acc[b] = fmaf(lv.x, mv.x, acc[b]);
            acc[b] = fmaf(lv.y, mv.y, acc[b]);
            acc[b] = fmaf(lv.z, mv.z, acc[b]);
            acc[b] = fmaf(lv.w, mv.w, acc[b]);
        }
    }
    if (h > 0) {
        #pragma unroll
        for (int b = 0; b < FBPB; ++b) partial[h-1][b][o] = acc[b];
    }
    __syncthreads();
    if (h == 0) {
        #pragma unroll
        for (int b = 0; b < FBPB; ++b) {
            const int bg = bag0 + b;
            if (bg < B)
                out[(size_t)bg*TYPES+o] =
                    acc[b] + partial[0][b][o] + partial[1][b][o] + partial[2][b][o];
        }
    }
}

extern "C" void kernel_launch(void* const* d_in, const int* in_sizes, int n_in,
                              void* d_out, int out_size, void* d_ws, size_t ws_size,
                              hipStream_t stream)
{
    const int*   feat = (const int*)d_in[0];
    const int*   offs = (const int*)d_in[1];
    const float* W    = (const float*)d_in[2];
    const float* L    = (const float*)d_in[3];
    float*       out  = (float*)d_out;
    const int T = in_sizes[0];
    const int B = in_sizes[1];

    const int nwave = (T + TPW - 1) / TPW;
    const size_t accBytes = (size_t)B * D * (sizeof(float) + sizeof(unsigned));
    const size_t need     = accBytes + (size_t)nwave * sizeof(int);
    if (ws_size < need) {
        const int grid = (B + FBPB - 1) / FBPB;
        embbag_fallback<<<grid, 512, 0, stream>>>(feat, offs, W, L, out, T, B);
        return;
    }

    float*    wsum    = (float*)d_ws;
    unsigned* wkey    = (unsigned*)((char*)d_ws + (size_t)B * D * sizeof(float));
    int*      waveseg = (int*)((char*)d_ws + accBytes);
    (void)hipMemsetAsync(d_ws, 0, accBytes, stream); // 0 == key(-inf): identity

    k0_seg<<<(nwave + 255) / 256, 256, 0, stream>>>(offs, waveseg, T, B, nwave);

    const int grid1 = (nwave + 3) / 4;       // 4 waves per 256-thr block
    k1_gather<<<grid1, 256, 0, stream>>>(feat, offs, waveseg, W, wsum, wkey, T, B);

    const int grid2 = (B + K2BPB - 1) / K2BPB;
    k2_linear<<<grid2, 256, 0, stream>>>(offs, wsum, wkey, L, out, T, B);
}

// Round 8
// 76.098 us; speedup vs baseline: 1.3636x; 1.0227x over previous
//
#include <hip/hip_runtime.h>
#include <cfloat>

// EmbeddingBag(mean) ++ EmbeddingBag(max) -> Linear(no bias)
// feat[T] i32, offs[B] i32 (sorted, offs[0]=0), W[100000][128] f32,
// L[128][256] f32 ; out: [B][128] f32
// Bag b = tokens [offs[b], offs[b+1]) (offs[B]=T); empty bag -> mean=max=0.
//
// Token-uniform two-kernel design:
//  k1: each wave owns TPW=64 contiguous tokens. Lane j holds token i0+j's id
//      and its segment (per-lane binary search, all 64 in parallel). Segment
//      boundaries = ballot mask; per piece: double-buffered 8-deep gather
//      pipeline, then 64-lane atomic flush (add / max-key).
//  k2: finalize mean/max from ws, dense [8x256]x[256x128] per block.

constexpr int D     = 128;
constexpr int TYPES = 128;
constexpr int TPW   = 64;    // tokens per wave in k1
constexpr int K2BPB = 8;     // bags per block in k2

// order-preserving float->uint key (monotone): uint-compare == float-compare
__device__ __forceinline__ unsigned fkey(float f) {
    unsigned b = __float_as_uint(f);
    return (b & 0x80000000u) ? ~b : (b | 0x80000000u);
}
__device__ __forceinline__ float funkey(unsigned k) {
    return __uint_as_float((k & 0x80000000u) ? (k & 0x7FFFFFFFu) : ~k);
}

// ---------------- k1: gather + per-segment partial reduce ------------------
__global__ __launch_bounds__(256, 4)
void k1_gather(const int* __restrict__ feat, const int* __restrict__ offs,
               const float* __restrict__ W,
               float* __restrict__ wsum, unsigned* __restrict__ wkey,
               int T, int B)
{
    const int wave = blockIdx.x * 4 + (threadIdx.x >> 6);
    const int lane = threadIdx.x & 63;
    const int slot = lane >> 5;   // 0/1
    const int g    = lane & 31;   // dims 4g..4g+3
    const int i0   = wave * TPW;
    if (i0 >= T) return;
    const int nvalid = min(TPW, T - i0);

    // lane j: token id + segment of token i0+j (clamped for j >= nvalid)
    const int pos    = i0 + min(lane, nvalid - 1);
    const int idxreg = feat[pos];

    int lo = 0, hi = B;                 // seg = last s with offs[s] <= pos
    while (lo < hi) {
        const int mid = (lo + hi) >> 1;
        if (offs[mid] <= pos) lo = mid + 1; else hi = mid;
    }
    const int seg_lane = lo - 1;

    // boundary mask: bit j = token j starts a new segment
    const int seg_prev = __shfl_up(seg_lane, 1);
    const unsigned long long bm = __ballot(lane > 0 && seg_lane != seg_prev);

    const float* __restrict__ Wg = W + 4 * g;

    int p = 0;
    while (p < nvalid) {
        const int seg = __shfl(seg_lane, p);
        // piece end: next boundary after p, clipped to nvalid
        const unsigned long long m = bm & ~((2ULL << p) - 1ULL);
        int pe = m ? (__ffsll((long long)m) - 1) : nvalid;
        pe = min(pe, nvalid);

        float4 s4 = make_float4(0.f, 0.f, 0.f, 0.f);
        float4 m4 = make_float4(-FLT_MAX, -FLT_MAX, -FLT_MAX, -FLT_MAX);

        int t = p;
        const int nb = (pe - p) >> 4;   // full 16-token batches (8 per slot)

        // ---- double-buffered pipeline: batch b+1 loads in flight while
        // ---- batch b is consumed (forces real MLP) ----
        float4 vA[8], vB[8];
        if (nb > 0) {
            #pragma unroll
            for (int u = 0; u < 8; ++u) {
                const int id = __shfl(idxreg, t + 2 * u + slot);
                vA[u] = *reinterpret_cast<const float4*>(Wg + (size_t)id * D);
            }
        }
        for (int b = 0; b < nb; ++b) {
            if (b + 1 < nb) {
                #pragma unroll
                for (int u = 0; u < 8; ++u) {
                    const int id = __shfl(idxreg, t + 16 + 2 * u + slot);
                    vB[u] = *reinterpret_cast<const float4*>(Wg + (size_t)id * D);
                }
            }
            #pragma unroll
            for (int u = 0; u < 8; ++u) {
                s4.x += vA[u].x; s4.y += vA[u].y;
                s4.z += vA[u].z; s4.w += vA[u].w;
                m4.x = fmaxf(m4.x, vA[u].x); m4.y = fmaxf(m4.y, vA[u].y);
                m4.z = fmaxf(m4.z, vA[u].z); m4.w = fmaxf(m4.w, vA[u].w);
            }
            #pragma unroll
            for (int u = 0; u < 8; ++u) vA[u] = vB[u];
            t += 16;
        }

        // ---- predicated tail (1..15 tokens), still 8-deep ----
        if (t < pe) {
            int  idx[8]; bool val[8];
            #pragma unroll
            for (int u = 0; u < 8; ++u) {
                const int tt = t + 2 * u + slot;
                val[u] = (tt < pe);
                idx[u] = __shfl(idxreg, val[u] ? tt : pe - 1);
            }
            float4 v[8];
            #pragma unroll
            for (int u = 0; u < 8; ++u)
                v[u] = *reinterpret_cast<const float4*>(Wg + (size_t)idx[u] * D);
            #pragma unroll
            for (int u = 0; u < 8; ++u) {
                s4.x += val[u] ? v[u].x : 0.f;
                s4.y += val[u] ? v[u].y : 0.f;
                s4.z += val[u] ? v[u].z : 0.f;
                s4.w += val[u] ? v[u].w : 0.f;
                m4.x = fmaxf(m4.x, val[u] ? v[u].x : -FLT_MAX);
                m4.y = fmaxf(m4.y, val[u] ? v[u].y : -FLT_MAX);
                m4.z = fmaxf(m4.z, val[u] ? v[u].z : -FLT_MAX);
                m4.w = fmaxf(m4.w, val[u] ? v[u].w : -FLT_MAX);
            }
        }

        // ---- merge slots (lane ^ 32), 64-lane atomic flush ----
        s4.x += __shfl_xor(s4.x, 32); s4.y += __shfl_xor(s4.y, 32);
        s4.z += __shfl_xor(s4.z, 32); s4.w += __shfl_xor(s4.w, 32);
        m4.x = fmaxf(m4.x, __shfl_xor(m4.x, 32));
        m4.y = fmaxf(m4.y, __shfl_xor(m4.y, 32));
        m4.z = fmaxf(m4.z, __shfl_xor(m4.z, 32));
        m4.w = fmaxf(m4.w, __shfl_xor(m4.w, 32));
        const float a0 = slot ? s4.z : s4.x;
        const float a1 = slot ? s4.w : s4.y;
        const float b0 = slot ? m4.z : m4.x;
        const float b1 = slot ? m4.w : m4.y;
        float*    ps = wsum + (size_t)seg * D + 4 * g + 2 * slot;
        unsigned* pk = wkey + (size_t)seg * D + 4 * g + 2 * slot;
        atomicAdd(ps + 0, a0); atomicAdd(ps + 1, a1);
        atomicMax(pk + 0, fkey(b0)); atomicMax(pk + 1, fkey(b1));

        p = pe;
    }
}

// ---------------- k2: finalize + linear -------------------------------------
__global__ __launch_bounds__(256, 8)
void k2_linear(const int* __restrict__ offs,
               const float* __restrict__ wsum, const unsigned* __restrict__ wkey,
               const float* __restrict__ L, float* __restrict__ out,
               int T, int B)
{
    __shared__ float men[K2BPB][2 * D];       // 8 KB
    __shared__ float partial[K2BPB][TYPES];   // 4 KB
    const int tid  = threadIdx.x;
    const int bag0 = blockIdx.x * K2BPB;

    // finalize mean / max into LDS (float4-vectorized)
    for (int e = tid; e < K2BPB * 2 * D / 4; e += 256) {
        const int r   = e >> 6;          // bag slot (64 float4 per bag row)
        const int c   = e & 63;          // float4 column
        const int bag = bag0 + r;
        float4 v = make_float4(0.f, 0.f, 0.f, 0.f);
        if (bag < B) {
            const int st  = offs[bag];
            const int en  = (bag + 1 < B) ? offs[bag + 1] : T;
            const int cnt = en - st;
            if (cnt > 0) {
                if (c < 32) {
                    const float4 s =
                        *reinterpret_cast<const float4*>(wsum + (size_t)bag * D + 4 * c);
                    const float inv = 1.0f / (float)cnt;
                    v = make_float4(s.x * inv, s.y * inv, s.z * inv, s.w * inv);
                } else {
                    const uint4 k =
                        *reinterpret_cast<const uint4*>(wkey + (size_t)bag * D + 4 * (c - 32));
                    v = make_float4(funkey(k.x), funkey(k.y),
                                    funkey(k.z), funkey(k.w));
                }
            }
        }
        *reinterpret_cast<float4*>(&men[r][4 * c]) = v;
    }
    __syncthreads();

    // out[bag][o] = sum_k men[bag][k] * L[o][k]
    const int o = tid & (TYPES - 1);
    const int h = tid >> 7;          // K-half: 0 or 1
    float acc[K2BPB];
    #pragma unroll
    for (int b = 0; b < K2BPB; ++b) acc[b] = 0.f;

    const float* Lrow = L + (size_t)o * (2 * D) + h * D;
    #pragma unroll 4
    for (int k4 = 0; k4 < D / 4; ++k4) {
        const float4 lv = *reinterpret_cast<const float4*>(Lrow + 4 * k4);
        #pragma unroll
        for (int b = 0; b < K2BPB; ++b) {
            const float4 mv = *reinterpret_cast<const float4*>(&men[b][h * D + 4 * k4]);
            acc[b] = fmaf(lv.x, mv.x, acc[b]);
            acc[b] = fmaf(lv.y, mv.y, acc[b]);
            acc[b] = fmaf(lv.z, mv.z, acc[b]);
            acc[b] = fmaf(lv.w, mv.w, acc[b]);
        }
    }
    if (h == 1) {
        #pragma unroll
        for (int b = 0; b < K2BPB; ++b) partial[b][o] = acc[b];
    }
    __syncthreads();
    if (h == 0) {
        #pragma unroll
        for (int b = 0; b < K2BPB; ++b) {
            const int bag = bag0 + b;
            if (bag < B)
                out[(size_t)bag * TYPES + o] = acc[b] + partial[b][o];
        }
    }
}

// ---------------- fallback (round-4 kernel) if ws is too small --------------
constexpr int FBPB = 4;
__global__ __launch_bounds__(512, 8)
void embbag_fallback(const int* __restrict__ feat, const int* __restrict__ offs,
                     const float* __restrict__ W, const float* __restrict__ L,
                     float* __restrict__ out, int T, int B)
{
    __shared__ float4 men[FBPB][64];
    __shared__ float4 redS[FBPB][2][32];
    __shared__ float4 redM[FBPB][2][32];
    __shared__ float  partial[3][FBPB][TYPES];
    const int tid = threadIdx.x, wv = tid >> 6, lane = tid & 63;
    const int bi = wv >> 1, wh = wv & 1, slot = lane >> 5, g = lane & 31;
    const int bag0 = blockIdx.x * FBPB, bag = bag0 + bi;
    int start = 0, end = 0;
    if (bag < B) { start = offs[bag]; end = (bag + 1 < B) ? offs[bag + 1] : T; }
    const int n = end - start, q = wh * 2 + slot;
    const int qa = start + (n * q) / 4, qb = start + (n * (q + 1)) / 4;
    float4 s4 = make_float4(0.f, 0.f, 0.f, 0.f);
    float4 m4 = make_float4(-FLT_MAX, -FLT_MAX, -FLT_MAX, -FLT_MAX);
    const float* Wg = W + 4 * g;
    int i = qa;
    for (; i + 8 <= qb; i += 8) {
        int idx[8];
        #pragma unroll
        for (int j = 0; j < 8; ++j) idx[j] = feat[i + j];
        #pragma unroll
        for (int j = 0; j < 8; ++j) {
            const float4 v = *reinterpret_cast<const float4*>(Wg + (size_t)idx[j] * D);
            s4.x += v.x; s4.y += v.y; s4.z += v.z; s4.w += v.w;
            m4.x = fmaxf(m4.x, v.x); m4.y = fmaxf(m4.y, v.y);
            m4.z = fmaxf(m4.z, v.z); m4.w = fmaxf(m4.w, v.w);
        }
    }
    for (; i < qb; ++i) {
        const int idx = feat[i];
        const float4 v = *reinterpret_cast<const float4*>(Wg + (size_t)idx * D);
        s4.x += v.x; s4.y += v.y; s4.z += v.z; s4.w += v.w;
        m4.x = fmaxf(m4.x, v.x); m4.y = fmaxf(m4.y, v.y);
        m4.z = fmaxf(m4.z, v.z); m4.w = fmaxf(m4.w, v.w);
    }
    s4.x += __shfl_xor(s4.x, 32); s4.y += __shfl_xor(s4.y, 32);
    s4.z += __shfl_xor(s4.z, 32); s4.w += __shfl_xor(s4.w, 32);
    m4.x = fmaxf(m4.x, __shfl_xor(m4.x, 32));
    m4.y = fmaxf(m4.y, __shfl_xor(m4.y, 32));
    m4.z = fmaxf(m4.z, __shfl_xor(m4.z, 32));
    m4.w = fmaxf(m4.w, __shfl_xor(m4.w, 32));
    if (lane < 32) { redS[bi][wh][g] = s4; redM[bi][wh][g] = m4; }
    __syncthreads();
    if (wh == 0 && lane < 32) {
        const float4 a0 = redS[bi][0][g], a1 = redS[bi][1][g];
        const float4 b0 = redM[bi][0][g], b1 = redM[bi][1][g];
        const bool empty = (n <= 0);
        const float inv = 1.0f / (float)(empty ? 1 : n);
        men[bi][g] = make_float4((a0.x+a1.x)*inv, (a0.y+a1.y)*inv,
                                 (a0.z+a1.z)*inv, (a0.w+a1.w)*inv);
        men[bi][32+g] = empty ? make_float4(0.f,0.f,0.f,0.f)
            : make_float4(fmaxf(b0.x,b1.x), fmaxf(b0.y,b1.y),
                          fmaxf(b0.z,b1.z), fmaxf(b0.w,b1.w));
    }
    __syncthreads();
    const int o = tid & (TYPES - 1), h = tid >> 7;
    float acc[FBPB];
    #pragma unroll
    for (int b = 0; b < FBPB; ++b) acc[b] = 0.f;
    const float* Lrow = L + (size_t)o * (2 * D) + h * 64;
    #pragma unroll
    for (int k4 = 0; k4 < 16; ++k4) {
        const float4 lv = *reinterpret_cast<const float4*>(Lrow + 4 * k4);
        #pragma unroll
        for (int b = 0; b < FBPB; ++b) {
            const float4 mv = men[b][h * 16 + k4];
            acc[b] = fmaf(lv.x, mv.x, acc[b]);
            acc[b] = fmaf(lv.y, mv.y, acc[b]);
            acc[b] = fmaf(lv.z, mv.z, acc[b]);
            acc[b] = fmaf(lv.w, mv.w, acc[b]);
        }
    }
    if (h > 0) {
        #pragma unroll
        for (int b = 0; b < FBPB; ++b) partial[h-1][b][o] = acc[b];
    }
    __syncthreads();
    if (h == 0) {
        #pragma unroll
        for (int b = 0; b < FBPB; ++b) {
            const int bg = bag0 + b;
            if (bg < B)
                out[(size_t)bg*TYPES+o] =
                    acc[b] + partial[0][b][o] + partial[1][b][o] + partial[2][b][o];
        }
    }
}

extern "C" void kernel_launch(void* const* d_in, const int* in_sizes, int n_in,
                              void* d_out, int out_size, void* d_ws, size_t ws_size,
                              hipStream_t stream)
{
    const int*   feat = (const int*)d_in[0];
    const int*   offs = (const int*)d_in[1];
    const float* W    = (const float*)d_in[2];
    const float* L    = (const float*)d_in[3];
    float*       out  = (float*)d_out;
    const int T = in_sizes[0];
    const int B = in_sizes[1];

    const size_t need = (size_t)B * D * (sizeof(float) + sizeof(unsigned));
    if (ws_size < need) {
        const int grid = (B + FBPB - 1) / FBPB;
        embbag_fallback<<<grid, 512, 0, stream>>>(feat, offs, W, L, out, T, B);
        return;
    }

    float*    wsum = (float*)d_ws;
    unsigned* wkey = (unsigned*)((char*)d_ws + (size_t)B * D * sizeof(float));
    (void)hipMemsetAsync(d_ws, 0, need, stream);  // 0 == key(-inf): identity

    const int nwave = (T + TPW - 1) / TPW;
    const int grid1 = (nwave + 3) / 4;       // 4 waves per 256-thr block
    k1_gather<<<grid1, 256, 0, stream>>>(feat, offs, W, wsum, wkey, T, B);

    const int grid2 = (B + K2BPB - 1) / K2BPB;
    k2_linear<<<grid2, 256, 0, stream>>>(offs, wsum, wkey, L, out, T, B);
}